// Round 23
// baseline (69.098 us; speedup 1.0000x reference)
//
#include <hip/hip_runtime.h>
#include <hip/hip_bf16.h>

#define NB 8
#define NN 512
#define NS 64
#define NH 16
#define ND 256

typedef __attribute__((ext_vector_type(8))) short bf16x8;
typedef __attribute__((ext_vector_type(4))) short bf16x4;
typedef __attribute__((ext_vector_type(4))) float f32x4;

__device__ inline float wred(float v) {
#pragma unroll
  for (int m = 32; m; m >>= 1) v += __shfl_xor(v, m, 64);
  return v;
}
__device__ inline float wred16(float v) {
#pragma unroll
  for (int m = 1; m < 16; m <<= 1) v += __shfl_xor(v, m, 64);
  return v;
}
__device__ inline ushort f2bf(float x) {
  __hip_bfloat16 h = __float2bfloat16(x);
  return *(ushort*)&h;
}

// =====================================================================
// K1: prep — R18 champion (R3 build + float4 emb gather).
// =====================================================================
__global__ __launch_bounds__(256) void k_prep(const int* __restrict__ pos,
                                              const float* __restrict__ emb,
                                              const float* __restrict__ H,
                                              const float* __restrict__ A,
                                              __hip_bfloat16* __restrict__ spb,
                                              __hip_bfloat16* __restrict__ Ab,
                                              __hip_bfloat16* __restrict__ Hb,
                                              __hip_bfloat16* __restrict__ HT,
                                              float* __restrict__ rdeg,
                                              float* __restrict__ h2) {
  __shared__ ushort T[64][68];
  int blk = blockIdx.x, tid = threadIdx.x;
  int wave = tid >> 6, lane = tid & 63;

  if (blk < 1024) {
    int t = blk * 256 + tid;               // [0, NB*NN*NS)
    int idx = pos[t];
    __hip_bfloat16* dst = spb + (size_t)t * NH;
    union { bf16x8 v; ushort h[8]; } u0, u1;
    if (idx == 0) {
#pragma unroll
      for (int i = 0; i < 8; ++i) { u0.h[i] = 0; u1.h[i] = 0; }
    } else {
      const float* er = emb + idx * NH;
      float4 e0 = *(const float4*)(er);
      float4 e1 = *(const float4*)(er + 4);
      float4 e2 = *(const float4*)(er + 8);
      float4 e3 = *(const float4*)(er + 12);
      u0.h[0] = f2bf(e0.x); u0.h[1] = f2bf(e0.y); u0.h[2] = f2bf(e0.z); u0.h[3] = f2bf(e0.w);
      u0.h[4] = f2bf(e1.x); u0.h[5] = f2bf(e1.y); u0.h[6] = f2bf(e1.z); u0.h[7] = f2bf(e1.w);
      u1.h[0] = f2bf(e2.x); u1.h[1] = f2bf(e2.y); u1.h[2] = f2bf(e2.z); u1.h[3] = f2bf(e2.w);
      u1.h[4] = f2bf(e3.x); u1.h[5] = f2bf(e3.y); u1.h[6] = f2bf(e3.z); u1.h[7] = f2bf(e3.w);
    }
    *(bf16x8*)(void*)dst = u0.v;
    *(bf16x8*)(void*)(dst + 8) = u1.v;
  } else if (blk < 2048) {
    int row = (blk - 1024) * 4 + wave;     // [0, NB*NN)
    const float* ar = A + (size_t)row * NN;
    float4 v0 = *(const float4*)(ar + lane * 8);
    float4 v1 = *(const float4*)(ar + lane * 8 + 4);
    float s = v0.x + v0.y + v0.z + v0.w + v1.x + v1.y + v1.z + v1.w;
    union { bf16x8 v; ushort h[8]; } u;
    u.h[0] = f2bf(v0.x); u.h[1] = f2bf(v0.y); u.h[2] = f2bf(v0.z); u.h[3] = f2bf(v0.w);
    u.h[4] = f2bf(v1.x); u.h[5] = f2bf(v1.y); u.h[6] = f2bf(v1.z); u.h[7] = f2bf(v1.w);
    *(bf16x8*)(void*)(Ab + (size_t)row * NN + lane * 8) = u.v;
    s = wred(s);
    if (lane == 0) rdeg[row] = rsqrtf(s);
  } else if (blk < 3072) {
    int row = (blk - 2048) * 4 + wave;     // [0, NB*NN)
    const float* hr = H + (size_t)row * ND;
    float4 v = *(const float4*)(hr + lane * 4);
    float ss = v.x * v.x + v.y * v.y + v.z * v.z + v.w * v.w;
    union { bf16x4 v4; ushort h[4]; } u;
    u.h[0] = f2bf(v.x); u.h[1] = f2bf(v.y); u.h[2] = f2bf(v.z); u.h[3] = f2bf(v.w);
    *(bf16x4*)(void*)(Hb + (size_t)row * ND + lane * 4) = u.v4;
    ss = wred(ss);
    if (lane == 0) h2[row] = ss;
  } else {
    int bi = blk - 3072;                   // [0, 256)
    int b = bi >> 5, r = bi & 31;
    int d0 = (r >> 3) * 64, n0 = (r & 7) * 64;
    int n = tid >> 2, c = (tid & 3) * 16;
    const float* src = H + ((size_t)b * NN + n0 + n) * ND + d0 + c;
#pragma unroll
    for (int q = 0; q < 4; ++q) {
      float4 f = *(const float4*)(src + q * 4);
      T[n][c + q * 4 + 0] = f2bf(f.x);
      T[n][c + q * 4 + 1] = f2bf(f.y);
      T[n][c + q * 4 + 2] = f2bf(f.z);
      T[n][c + q * 4 + 3] = f2bf(f.w);
    }
    __syncthreads();
    int d = tid >> 2, nc = (tid & 3) * 16;
    union { bf16x8 v; ushort h[8]; } o0, o1;
#pragma unroll
    for (int i = 0; i < 8; ++i) { o0.h[i] = T[nc + i][d]; o1.h[i] = T[nc + 8 + i][d]; }
    __hip_bfloat16* dst = HT + ((size_t)b * ND + d0 + d) * NN + n0 + nc;
    *(bf16x8*)(void*)dst = o0.v;
    *(bf16x8*)(void*)(dst + 8) = o1.v;
  }
}

// =====================================================================
// K2: M = rdeg ⊙ (A·H) — R4's 512-block 16x32-tile variant (proven).
// =====================================================================
__global__ __launch_bounds__(256) void k_gemmM(const __hip_bfloat16* __restrict__ Ab,
                                               const __hip_bfloat16* __restrict__ HT,
                                               const float* __restrict__ rdeg,
                                               __hip_bfloat16* __restrict__ Mb,
                                               float* __restrict__ m2p) {
  int wave = threadIdx.x >> 6, lane = threadIdx.x & 63;
  int b = blockIdx.x & 7, t = blockIdx.x >> 3;   // t in [0,64)
  int tile = t * 4 + wave;                       // [0,256) = 32 rt x 8 ct
  int rt = tile >> 3, ct = tile & 7;
  int r0 = rt * 16, c0 = ct * 32;
  int rl = lane & 15, g4 = lane >> 4;
  const __hip_bfloat16* X = Ab + (size_t)b * NN * NN;
  const __hip_bfloat16* Y = HT + (size_t)b * ND * NN;
  f32x4 acc[2];
#pragma unroll
  for (int j = 0; j < 2; ++j) { acc[j][0] = 0.f; acc[j][1] = 0.f; acc[j][2] = 0.f; acc[j][3] = 0.f; }
#pragma unroll
  for (int kk = 0; kk < NN / 32; ++kk) {
    int kb = kk * 32 + g4 * 8;
    bf16x8 a = *(const bf16x8*)(const void*)(X + (size_t)(r0 + rl) * NN + kb);
#pragma unroll
    for (int j = 0; j < 2; ++j) {
      bf16x8 bv = *(const bf16x8*)(const void*)(Y + (size_t)(c0 + j * 16 + rl) * NN + kb);
      acc[j] = __builtin_amdgcn_mfma_f32_16x16x32_bf16(a, bv, acc[j], 0, 0, 0);
    }
  }
#pragma unroll
  for (int r = 0; r < 4; ++r) {
    int row = r0 + g4 * 4 + r;
    float rd = rdeg[b * NN + row];
    float ss = 0.f;
#pragma unroll
    for (int j = 0; j < 2; ++j) {
      float m = rd * acc[j][r];
      int col = c0 + j * 16 + rl;
      Mb[((size_t)b * NN + row) * ND + col] = __float2bfloat16(m);
      ss += m * m;
    }
    ss = wred16(ss);
    if (rl == 0) m2p[(size_t)ct * (NB * NN) + b * NN + row] = ss;
  }
}

// =====================================================================
// K3 v17: column-split tiles — 1024 blocks x 256 thr, block =
// (b, rt in [0,8), ct in [0,16)) owning a 64x32 output tile.
// 4 independent blocks/CU (vs champion's 2): 4 phase-offset streams
// per CU keep the store pipe covered while other blocks are in their
// store-silent phases. G computed once per disjoint tile (no dup).
// Phase 1: 4 waves x (16 rows x 32 cols) -> Gt[64][36].
// greg hoist (swapped layout, 8 f32x4). Phase 2: wave w -> heads
// w*4+{0..3}: 4 row-frags x 2 col-frags, swapped MFMA -> acc[4][2];
// epilogue: b128 bounce into Ot[16][36], 2 store instrs/strip, each
// = 8 rows x 128 B full lines.
// =====================================================================
__global__ __launch_bounds__(256) void k_out(const __hip_bfloat16* __restrict__ Hb,
                                             const __hip_bfloat16* __restrict__ Mb,
                                             const __hip_bfloat16* __restrict__ spb,
                                             const float* __restrict__ h2,
                                             const float* __restrict__ m2p,
                                             const float* __restrict__ sigma,
                                             float* __restrict__ out) {
  __shared__ __align__(16) float Gt[64][36];
  __shared__ __align__(16) float Ot[4][16][36];   // per-wave strip buffer
  __shared__ float h2s[64], m2s[32];
  int b = blockIdx.x & 7;
  int t2 = blockIdx.x >> 3;                 // [0,128)
  int ct = t2 & 15, rt = t2 >> 4;
  int r0 = rt * 64, c0 = ct * 32;
  int tid = threadIdx.x;
  int wave = tid >> 6, lane = tid & 63;
  int rl = lane & 15, g4 = lane >> 4;

  if (tid < 64) {
    h2s[tid] = h2[b * NN + r0 + tid];
  } else if (tid < 96) {
    int c = tid - 64;
    float s = 0.f;
#pragma unroll
    for (int p = 0; p < 8; ++p) s += m2p[(size_t)p * (NB * NN) + b * NN + c0 + c];
    m2s[c] = s;
  }
  __syncthreads();

  // ---- phase 1: G once. wave w: rows w*16..+15, all 32 cols.
  {
    const __hip_bfloat16* X = Hb + (size_t)b * NN * ND;
    const __hip_bfloat16* Y = Mb + (size_t)b * NN * ND;
    int rw = wave * 16;
    f32x4 acc[2];
#pragma unroll
    for (int j = 0; j < 2; ++j) { acc[j][0] = 0.f; acc[j][1] = 0.f; acc[j][2] = 0.f; acc[j][3] = 0.f; }
#pragma unroll
    for (int kk = 0; kk < ND / 32; ++kk) {
      int kb = kk * 32 + g4 * 8;
      bf16x8 a = *(const bf16x8*)(const void*)(X + (size_t)(r0 + rw + rl) * ND + kb);
#pragma unroll
      for (int j = 0; j < 2; ++j) {
        bf16x8 bv = *(const bf16x8*)(const void*)(Y + (size_t)(c0 + j * 16 + rl) * ND + kb);
        acc[j] = __builtin_amdgcn_mfma_f32_16x16x32_bf16(a, bv, acc[j], 0, 0, 0);
      }
    }
    float sg = sigma[0];
    float inv = 0.5f / (sg * sg);
#pragma unroll
    for (int j = 0; j < 2; ++j)
#pragma unroll
      for (int r = 0; r < 4; ++r) {
        int rowl = rw + g4 * 4 + r;
        int col = j * 16 + rl;
        float d2 = h2s[rowl] + m2s[col] - 2.0f * acc[j][r];
        Gt[rowl][col] = __expf(-d2 * inv);
      }
  }
  __syncthreads();

  // ---- hoist G to registers in the swapped layout (8 b128 reads)
  f32x4 greg[4][2];
#pragma unroll
  for (int i = 0; i < 4; ++i)
#pragma unroll
    for (int j = 0; j < 2; ++j)
      greg[i][j] = *(const f32x4*)&Gt[i * 16 + rl][j * 16 + g4 * 4];

  // ---- phase 2: wave w -> heads w*4 + {0..3}
  float (*Ow)[36] = Ot[wave];
#pragma unroll 1
  for (int hh = 0; hh < 4; ++hh) {
    int h = wave * 4 + hh;
    const __hip_bfloat16* Xs = spb + ((size_t)b * NH + h) * NN * NS;
    f32x4 acc[4][2];
#pragma unroll
    for (int i = 0; i < 4; ++i)
#pragma unroll
      for (int j = 0; j < 2; ++j) { acc[i][j][0] = 0.f; acc[i][j][1] = 0.f; acc[i][j][2] = 0.f; acc[i][j][3] = 0.f; }
#pragma unroll
    for (int kk = 0; kk < NS / 32; ++kk) {
      int kb = kk * 32 + g4 * 8;
      bf16x8 a[4], bv[2];
#pragma unroll
      for (int i = 0; i < 4; ++i)
        a[i] = *(const bf16x8*)(const void*)(Xs + (size_t)(r0 + i * 16 + rl) * NS + kb);
#pragma unroll
      for (int j = 0; j < 2; ++j)
        bv[j] = *(const bf16x8*)(const void*)(Xs + (size_t)(c0 + j * 16 + rl) * NS + kb);
      // SWAPPED operands (R7/R18-verified): acc[i][j] = rows r0+i16+rl,
      // cols c0+j16+g4*4..+3 of the output tile (Gram symmetry).
#pragma unroll
      for (int i = 0; i < 4; ++i)
#pragma unroll
        for (int j = 0; j < 2; ++j)
          acc[i][j] = __builtin_amdgcn_mfma_f32_16x16x32_bf16(bv[j], a[i], acc[i][j], 0, 0, 0);
    }
    float* ob = out + ((size_t)b * NH + h) * NN * NN;
    // epilogue: G-add in regs, b128 bounce, full-line stores.
#pragma unroll
    for (int i = 0; i < 4; ++i) {
#pragma unroll
      for (int j = 0; j < 2; ++j) {
        f32x4 w = acc[i][j] + greg[i][j];
        *(f32x4*)&Ow[rl][j * 16 + g4 * 4] = w;   // ds_write_b128, row rl
      }
      asm volatile("s_waitcnt lgkmcnt(0)" ::: "memory");
      // 2 store instrs: it-th covers rows it*8..+7, each row 128 B line.
#pragma unroll
      for (int it = 0; it < 2; ++it) {
        int row = it * 8 + (lane >> 3);
        int col = (lane & 7) * 4;
        f32x4 o = *(const f32x4*)&Ow[row][col];
        *(f32x4*)&ob[(size_t)(r0 + i * 16 + row) * NN + c0 + col] = o;
      }
      asm volatile("" ::: "memory");  // keep strip i's reads before strip i+1's writes
    }
  }
}

extern "C" void kernel_launch(void* const* d_in, const int* in_sizes, int n_in,
                              void* d_out, int out_size, void* d_ws, size_t ws_size,
                              hipStream_t stream) {
  const int* pos = (const int*)d_in[0];
  const float* H = (const float*)d_in[1];
  const float* A = (const float*)d_in[2];
  const float* sigma = (const float*)d_in[3];
  const float* emb = (const float*)d_in[4];
  // d_in[5] (vt_weight) only affects the sliced-off padded row/col -> unused.
  float* out = (float*)d_out;

  char* ws = (char*)d_ws;
  size_t off = 0;
  auto alloc = [&](size_t bytes) -> void* {
    void* p = ws + off;
    off = (off + bytes + 255) & ~(size_t)255;
    return p;
  };
  __hip_bfloat16* spb = (__hip_bfloat16*)alloc((size_t)NB * NH * NN * NS * 2);
  __hip_bfloat16* Ab  = (__hip_bfloat16*)alloc((size_t)NB * NN * NN * 2);
  __hip_bfloat16* Hb  = (__hip_bfloat16*)alloc((size_t)NB * NN * ND * 2);
  __hip_bfloat16* HT  = (__hip_bfloat16*)alloc((size_t)NB * ND * NN * 2);
  __hip_bfloat16* Mb  = (__hip_bfloat16*)alloc((size_t)NB * NN * ND * 2);
  float* m2p  = (float*)alloc((size_t)8 * NB * NN * 4);
  float* rdeg = (float*)alloc((size_t)NB * NN * 4);
  float* h2   = (float*)alloc((size_t)NB * NN * 4);

  k_prep<<<3328, 256, 0, stream>>>(pos, emb, H, A, spb, Ab, Hb, HT, rdeg, h2);
  k_gemmM<<<512, 256, 0, stream>>>(Ab, HT, rdeg, Mb, m2p);
  k_out<<<1024, 256, 0, stream>>>(Hb, Mb, spb, h2, m2p, sigma, out);
}

// Round 24
// 62.873 us; speedup vs baseline: 1.0990x; 1.0990x over previous
//
#include <hip/hip_runtime.h>
#include <hip/hip_bf16.h>

#define NB 8
#define NN 512
#define NS 64
#define NH 16
#define ND 256

typedef __attribute__((ext_vector_type(8))) short bf16x8;
typedef __attribute__((ext_vector_type(4))) short bf16x4;
typedef __attribute__((ext_vector_type(4))) float f32x4;

__device__ inline float wred(float v) {
#pragma unroll
  for (int m = 32; m; m >>= 1) v += __shfl_xor(v, m, 64);
  return v;
}
__device__ inline float wred16(float v) {
#pragma unroll
  for (int m = 1; m < 16; m <<= 1) v += __shfl_xor(v, m, 64);
  return v;
}
__device__ inline ushort f2bf(float x) {
  __hip_bfloat16 h = __float2bfloat16(x);
  return *(ushort*)&h;
}

// =====================================================================
// K1: prep — R18 champion (R3 build + float4 emb gather).
// =====================================================================
__global__ __launch_bounds__(256) void k_prep(const int* __restrict__ pos,
                                              const float* __restrict__ emb,
                                              const float* __restrict__ H,
                                              const float* __restrict__ A,
                                              __hip_bfloat16* __restrict__ spb,
                                              __hip_bfloat16* __restrict__ Ab,
                                              __hip_bfloat16* __restrict__ Hb,
                                              __hip_bfloat16* __restrict__ HT,
                                              float* __restrict__ rdeg,
                                              float* __restrict__ h2) {
  __shared__ ushort T[64][68];
  int blk = blockIdx.x, tid = threadIdx.x;
  int wave = tid >> 6, lane = tid & 63;

  if (blk < 1024) {
    int t = blk * 256 + tid;               // [0, NB*NN*NS)
    int idx = pos[t];
    __hip_bfloat16* dst = spb + (size_t)t * NH;
    union { bf16x8 v; ushort h[8]; } u0, u1;
    if (idx == 0) {
#pragma unroll
      for (int i = 0; i < 8; ++i) { u0.h[i] = 0; u1.h[i] = 0; }
    } else {
      const float* er = emb + idx * NH;
      float4 e0 = *(const float4*)(er);
      float4 e1 = *(const float4*)(er + 4);
      float4 e2 = *(const float4*)(er + 8);
      float4 e3 = *(const float4*)(er + 12);
      u0.h[0] = f2bf(e0.x); u0.h[1] = f2bf(e0.y); u0.h[2] = f2bf(e0.z); u0.h[3] = f2bf(e0.w);
      u0.h[4] = f2bf(e1.x); u0.h[5] = f2bf(e1.y); u0.h[6] = f2bf(e1.z); u0.h[7] = f2bf(e1.w);
      u1.h[0] = f2bf(e2.x); u1.h[1] = f2bf(e2.y); u1.h[2] = f2bf(e2.z); u1.h[3] = f2bf(e2.w);
      u1.h[4] = f2bf(e3.x); u1.h[5] = f2bf(e3.y); u1.h[6] = f2bf(e3.z); u1.h[7] = f2bf(e3.w);
    }
    *(bf16x8*)(void*)dst = u0.v;
    *(bf16x8*)(void*)(dst + 8) = u1.v;
  } else if (blk < 2048) {
    int row = (blk - 1024) * 4 + wave;     // [0, NB*NN)
    const float* ar = A + (size_t)row * NN;
    float4 v0 = *(const float4*)(ar + lane * 8);
    float4 v1 = *(const float4*)(ar + lane * 8 + 4);
    float s = v0.x + v0.y + v0.z + v0.w + v1.x + v1.y + v1.z + v1.w;
    union { bf16x8 v; ushort h[8]; } u;
    u.h[0] = f2bf(v0.x); u.h[1] = f2bf(v0.y); u.h[2] = f2bf(v0.z); u.h[3] = f2bf(v0.w);
    u.h[4] = f2bf(v1.x); u.h[5] = f2bf(v1.y); u.h[6] = f2bf(v1.z); u.h[7] = f2bf(v1.w);
    *(bf16x8*)(void*)(Ab + (size_t)row * NN + lane * 8) = u.v;
    s = wred(s);
    if (lane == 0) rdeg[row] = rsqrtf(s);
  } else if (blk < 3072) {
    int row = (blk - 2048) * 4 + wave;     // [0, NB*NN)
    const float* hr = H + (size_t)row * ND;
    float4 v = *(const float4*)(hr + lane * 4);
    float ss = v.x * v.x + v.y * v.y + v.z * v.z + v.w * v.w;
    union { bf16x4 v4; ushort h[4]; } u;
    u.h[0] = f2bf(v.x); u.h[1] = f2bf(v.y); u.h[2] = f2bf(v.z); u.h[3] = f2bf(v.w);
    *(bf16x4*)(void*)(Hb + (size_t)row * ND + lane * 4) = u.v4;
    ss = wred(ss);
    if (lane == 0) h2[row] = ss;
  } else {
    int bi = blk - 3072;                   // [0, 256)
    int b = bi >> 5, r = bi & 31;
    int d0 = (r >> 3) * 64, n0 = (r & 7) * 64;
    int n = tid >> 2, c = (tid & 3) * 16;
    const float* src = H + ((size_t)b * NN + n0 + n) * ND + d0 + c;
#pragma unroll
    for (int q = 0; q < 4; ++q) {
      float4 f = *(const float4*)(src + q * 4);
      T[n][c + q * 4 + 0] = f2bf(f.x);
      T[n][c + q * 4 + 1] = f2bf(f.y);
      T[n][c + q * 4 + 2] = f2bf(f.z);
      T[n][c + q * 4 + 3] = f2bf(f.w);
    }
    __syncthreads();
    int d = tid >> 2, nc = (tid & 3) * 16;
    union { bf16x8 v; ushort h[8]; } o0, o1;
#pragma unroll
    for (int i = 0; i < 8; ++i) { o0.h[i] = T[nc + i][d]; o1.h[i] = T[nc + 8 + i][d]; }
    __hip_bfloat16* dst = HT + ((size_t)b * ND + d0 + d) * NN + n0 + nc;
    *(bf16x8*)(void*)dst = o0.v;
    *(bf16x8*)(void*)(dst + 8) = o1.v;
  }
}

// =====================================================================
// K2: M = rdeg ⊙ (A·H) — R4's 512-block 16x32-tile variant (proven).
// =====================================================================
__global__ __launch_bounds__(256) void k_gemmM(const __hip_bfloat16* __restrict__ Ab,
                                               const __hip_bfloat16* __restrict__ HT,
                                               const float* __restrict__ rdeg,
                                               __hip_bfloat16* __restrict__ Mb,
                                               float* __restrict__ m2p) {
  int wave = threadIdx.x >> 6, lane = threadIdx.x & 63;
  int b = blockIdx.x & 7, t = blockIdx.x >> 3;   // t in [0,64)
  int tile = t * 4 + wave;                       // [0,256) = 32 rt x 8 ct
  int rt = tile >> 3, ct = tile & 7;
  int r0 = rt * 16, c0 = ct * 32;
  int rl = lane & 15, g4 = lane >> 4;
  const __hip_bfloat16* X = Ab + (size_t)b * NN * NN;
  const __hip_bfloat16* Y = HT + (size_t)b * ND * NN;
  f32x4 acc[2];
#pragma unroll
  for (int j = 0; j < 2; ++j) { acc[j][0] = 0.f; acc[j][1] = 0.f; acc[j][2] = 0.f; acc[j][3] = 0.f; }
#pragma unroll
  for (int kk = 0; kk < NN / 32; ++kk) {
    int kb = kk * 32 + g4 * 8;
    bf16x8 a = *(const bf16x8*)(const void*)(X + (size_t)(r0 + rl) * NN + kb);
#pragma unroll
    for (int j = 0; j < 2; ++j) {
      bf16x8 bv = *(const bf16x8*)(const void*)(Y + (size_t)(c0 + j * 16 + rl) * NN + kb);
      acc[j] = __builtin_amdgcn_mfma_f32_16x16x32_bf16(a, bv, acc[j], 0, 0, 0);
    }
  }
#pragma unroll
  for (int r = 0; r < 4; ++r) {
    int row = r0 + g4 * 4 + r;
    float rd = rdeg[b * NN + row];
    float ss = 0.f;
#pragma unroll
    for (int j = 0; j < 2; ++j) {
      float m = rd * acc[j][r];
      int col = c0 + j * 16 + rl;
      Mb[((size_t)b * NN + row) * ND + col] = __float2bfloat16(m);
      ss += m * m;
    }
    ss = wred16(ss);
    if (rl == 0) m2p[(size_t)ct * (NB * NN) + b * NN + row] = ss;
  }
}

// =====================================================================
// K3 v16 (champion, R22 = 62.98 µs): fence-free R18 epilogue.
// 512 blocks x 256 thr (4 waves). Phase 1: G -> Gt once, all 4 waves.
// G hoisted to regs (swapped layout). Phase 2: wave w -> heads w*4+{0..3},
// swapped-operand gram, b128 bounce, 1024 B contiguous stores; compiler
// orders Ow write->read via precise counted lgkmcnt (no asm fences).
// =====================================================================
__global__ __launch_bounds__(256) void k_out(const __hip_bfloat16* __restrict__ Hb,
                                             const __hip_bfloat16* __restrict__ Mb,
                                             const __hip_bfloat16* __restrict__ spb,
                                             const float* __restrict__ h2,
                                             const float* __restrict__ m2p,
                                             const float* __restrict__ sigma,
                                             float* __restrict__ out) {
  __shared__ __align__(16) float Gt[64][68];
  __shared__ __align__(16) float Ot[4][16][72];   // per-wave strip buffer
  __shared__ float h2s[64], m2s[64];
  int b = blockIdx.x & 7;
  int t2 = blockIdx.x >> 3;                 // [0,64)
  int ct = t2 & 7, rt = t2 >> 3;
  int r0 = rt * 64, c0 = ct * 64;
  int tid = threadIdx.x;
  int wave = tid >> 6, lane = tid & 63;
  int rl = lane & 15, g4 = lane >> 4;

  if (tid < 64) {
    h2s[tid] = h2[b * NN + r0 + tid];
  } else if (tid < 128) {
    int c = tid - 64;
    float s = 0.f;
#pragma unroll
    for (int p = 0; p < 8; ++p) s += m2p[(size_t)p * (NB * NN) + b * NN + c0 + c];
    m2s[c] = s;
  }
  __syncthreads();

  // ---- phase 1: G once, ALL 4 waves. wave w: rows w*16..+15, 64 cols.
  {
    const __hip_bfloat16* X = Hb + (size_t)b * NN * ND;
    const __hip_bfloat16* Y = Mb + (size_t)b * NN * ND;
    int rw = wave * 16;
    f32x4 acc[4];
#pragma unroll
    for (int j = 0; j < 4; ++j) { acc[j][0] = 0.f; acc[j][1] = 0.f; acc[j][2] = 0.f; acc[j][3] = 0.f; }
#pragma unroll
    for (int kk = 0; kk < ND / 32; ++kk) {
      int kb = kk * 32 + g4 * 8;
      bf16x8 a = *(const bf16x8*)(const void*)(X + (size_t)(r0 + rw + rl) * ND + kb);
#pragma unroll
      for (int j = 0; j < 4; ++j) {
        bf16x8 bv = *(const bf16x8*)(const void*)(Y + (size_t)(c0 + j * 16 + rl) * ND + kb);
        acc[j] = __builtin_amdgcn_mfma_f32_16x16x32_bf16(a, bv, acc[j], 0, 0, 0);
      }
    }
    float sg = sigma[0];
    float inv = 0.5f / (sg * sg);
#pragma unroll
    for (int j = 0; j < 4; ++j)
#pragma unroll
      for (int r = 0; r < 4; ++r) {
        int rowl = rw + g4 * 4 + r;
        int col = j * 16 + rl;
        float d2 = h2s[rowl] + m2s[col] - 2.0f * acc[j][r];
        Gt[rowl][col] = __expf(-d2 * inv);
      }
  }
  __syncthreads();

  // ---- hoist G to registers in the swapped layout (16 b128 reads, once)
  f32x4 greg[4][4];
#pragma unroll
  for (int i = 0; i < 4; ++i)
#pragma unroll
    for (int j = 0; j < 4; ++j)
      greg[i][j] = *(const f32x4*)&Gt[i * 16 + rl][j * 16 + g4 * 4];

  // ---- phase 2: wave w -> heads w*4 + {0..3}
  float (*Ow)[72] = Ot[wave];
#pragma unroll 1
  for (int hh = 0; hh < 4; ++hh) {
    int h = wave * 4 + hh;
    const __hip_bfloat16* Xs = spb + ((size_t)b * NH + h) * NN * NS;
    f32x4 acc[4][4];
#pragma unroll
    for (int i = 0; i < 4; ++i)
#pragma unroll
      for (int j = 0; j < 4; ++j) { acc[i][j][0] = 0.f; acc[i][j][1] = 0.f; acc[i][j][2] = 0.f; acc[i][j][3] = 0.f; }
#pragma unroll
    for (int kk = 0; kk < NS / 32; ++kk) {
      int kb = kk * 32 + g4 * 8;
      bf16x8 a[4], bv[4];
#pragma unroll
      for (int i = 0; i < 4; ++i)
        a[i] = *(const bf16x8*)(const void*)(Xs + (size_t)(r0 + i * 16 + rl) * NS + kb);
#pragma unroll
      for (int j = 0; j < 4; ++j)
        bv[j] = *(const bf16x8*)(const void*)(Xs + (size_t)(c0 + j * 16 + rl) * NS + kb);
      // SWAPPED operands (R7/R18-verified): acc[i][j] = rows r0+i16+rl,
      // cols c0+j16+g4*4..+3 of the output tile (Gram symmetry).
#pragma unroll
      for (int i = 0; i < 4; ++i)
#pragma unroll
        for (int j = 0; j < 4; ++j)
          acc[i][j] = __builtin_amdgcn_mfma_f32_16x16x32_bf16(bv[j], a[i], acc[i][j], 0, 0, 0);
    }
    float* ob = out + ((size_t)b * NH + h) * NN * NN;
    // epilogue: G-add in regs, b128 bounce, 1024 B contiguous stores.
    // NO asm fences: compiler orders Ow write->read via precise lgkmcnt.
#pragma unroll
    for (int i = 0; i < 4; ++i) {
#pragma unroll
      for (int j = 0; j < 4; ++j) {
        f32x4 w = acc[i][j] + greg[i][j];
        *(f32x4*)&Ow[rl][j * 16 + g4 * 4] = w;   // ds_write_b128, row rl
      }
#pragma unroll
      for (int it = 0; it < 4; ++it) {
        int row = it * 4 + g4;
        int col = rl * 4;
        f32x4 o = *(const f32x4*)&Ow[row][col];
        *(f32x4*)&ob[(size_t)(r0 + i * 16 + row) * NN + c0 + col] = o;
      }
    }
  }
}

extern "C" void kernel_launch(void* const* d_in, const int* in_sizes, int n_in,
                              void* d_out, int out_size, void* d_ws, size_t ws_size,
                              hipStream_t stream) {
  const int* pos = (const int*)d_in[0];
  const float* H = (const float*)d_in[1];
  const float* A = (const float*)d_in[2];
  const float* sigma = (const float*)d_in[3];
  const float* emb = (const float*)d_in[4];
  // d_in[5] (vt_weight) only affects the sliced-off padded row/col -> unused.
  float* out = (float*)d_out;

  char* ws = (char*)d_ws;
  size_t off = 0;
  auto alloc = [&](size_t bytes) -> void* {
    void* p = ws + off;
    off = (off + bytes + 255) & ~(size_t)255;
    return p;
  };
  __hip_bfloat16* spb = (__hip_bfloat16*)alloc((size_t)NB * NH * NN * NS * 2);
  __hip_bfloat16* Ab  = (__hip_bfloat16*)alloc((size_t)NB * NN * NN * 2);
  __hip_bfloat16* Hb  = (__hip_bfloat16*)alloc((size_t)NB * NN * ND * 2);
  __hip_bfloat16* HT  = (__hip_bfloat16*)alloc((size_t)NB * ND * NN * 2);
  __hip_bfloat16* Mb  = (__hip_bfloat16*)alloc((size_t)NB * NN * ND * 2);
  float* m2p  = (float*)alloc((size_t)8 * NB * NN * 4);
  float* rdeg = (float*)alloc((size_t)NB * NN * 4);
  float* h2   = (float*)alloc((size_t)NB * NN * 4);

  k_prep<<<3328, 256, 0, stream>>>(pos, emb, H, A, spb, Ab, Hb, HT, rdeg, h2);
  k_gemmM<<<512, 256, 0, stream>>>(Ab, HT, rdeg, Mb, m2p);
  k_out<<<512, 256, 0, stream>>>(Hb, Mb, spb, h2, m2p, sigma, out);
}